// Round 18
// baseline (257.036 us; speedup 1.0000x reference)
//
#include <hip/hip_runtime.h>
#include <stdint.h>

typedef float f32x4 __attribute__((ext_vector_type(4)));
typedef short s16x8 __attribute__((ext_vector_type(8)));
typedef short s16x4 __attribute__((ext_vector_type(4)));
typedef unsigned short ushort_t;

#define B_  32
#define N_  3136
#define C_  384
#define H_  8
#define DH_ 48
#define M_  196
#define ROWS  (B_*N_)   // 100352
#define PROWS (B_*M_)   // 6272

// RNE bf16 (reference-grade)
static __device__ __forceinline__ ushort_t f2bf(float f) {
  union { float f; uint32_t u; } v; v.f = f;
  uint32_t r = (v.u + 0x7fffu + ((v.u >> 16) & 1u)) >> 16;
  return (ushort_t)r;
}
// round-half-up bf16: 2 VALU inst; differs from RNE only on exact ties
static __device__ __forceinline__ ushort_t f2bf_fast(float f) {
  union { float f; uint32_t u; } v; v.f = f;
  return (ushort_t)((v.u + 0x8000u) >> 16);
}
// packed f32x2 -> bf16x2, T12-verified recipe (m214v22)
static __device__ __forceinline__ uint32_t pkbf(float lo, float hi) {
  uint32_t r;
  asm("v_cvt_pk_bf16_f32 %0, %1, %2" : "=v"(r) : "v"(lo), "v"(hi));
  return r;
}

static __device__ __forceinline__ f32x4 mfma_16x16x32(s16x8 a, s16x8 b, f32x4 c) {
  return __builtin_amdgcn_mfma_f32_16x16x32_bf16(a, b, c, 0, 0, 0);
}

static __device__ __forceinline__ f32x4 mfma_16x16x16(s16x4 a, s16x4 b, f32x4 c) {
#if __has_builtin(__builtin_amdgcn_mfma_f32_16x16x16_bf16)
  return __builtin_amdgcn_mfma_f32_16x16x16_bf16(a, b, c, 0, 0, 0);
#elif __has_builtin(__builtin_amdgcn_mfma_f32_16x16x16bf16_1k)
  return __builtin_amdgcn_mfma_f32_16x16x16bf16_1k(a, b, c, 0, 0, 0);
#else
  f32x4 d;
  asm("v_mfma_f32_16x16x16_bf16 %0, %1, %2, %3" : "=v"(d) : "v"(a), "v"(b), "v"(c));
  return d;
#endif
}

static __device__ __forceinline__ void gload_lds16(const void* g, void* l) {
  __builtin_amdgcn_global_load_lds(
      (const __attribute__((address_space(1))) void*)(uintptr_t)g,
      (__attribute__((address_space(3))) void*)(uint32_t)(uintptr_t)l,
      16, 0, 0);
}

// ---------------- LayerNorm + exact GELU, fp32 -> bf16 ----------------
__global__ __launch_bounds__(256) void k_ln_gelu(
    const float* __restrict__ x, const float* __restrict__ lnw,
    const float* __restrict__ lnb, ushort_t* __restrict__ x16) {
  int row = blockIdx.x * 4 + (threadIdx.x >> 6);
  int lane = threadIdx.x & 63;
  const float2* xr = (const float2*)(x + (size_t)row * C_);
  float2 v0 = xr[lane], v1 = xr[lane + 64], v2 = xr[lane + 128];
  float s  = v0.x + v0.y + v1.x + v1.y + v2.x + v2.y;
  float ss = v0.x*v0.x + v0.y*v0.y + v1.x*v1.x + v1.y*v1.y + v2.x*v2.x + v2.y*v2.y;
#pragma unroll
  for (int off = 1; off < 64; off <<= 1) {
    s  += __shfl_xor(s, off);
    ss += __shfl_xor(ss, off);
  }
  float mu = s * (1.0f / C_);
  float rs = rsqrtf(ss * (1.0f / C_) - mu * mu + 1e-6f);
  const float2* wr = (const float2*)lnw;
  const float2* br = (const float2*)lnb;
  uint32_t* outp = (uint32_t*)(x16 + (size_t)row * C_);
#pragma unroll
  for (int t = 0; t < 3; ++t) {
    int idx = lane + t * 64;
    float2 v = (t == 0) ? v0 : ((t == 1) ? v1 : v2);
    float2 w = wr[idx], bb = br[idx];
    float a0 = (v.x - mu) * rs * w.x + bb.x;
    float a1 = (v.y - mu) * rs * w.y + bb.y;
    a0 = 0.5f * a0 * (1.0f + erff(a0 * 0.70710678118654752440f));
    a1 = 0.5f * a1 * (1.0f + erff(a1 * 0.70710678118654752440f));
    outp[idx] = (uint32_t)f2bf_fast(a0) | ((uint32_t)f2bf_fast(a1) << 16);
  }
}

// ---------------- weight/query conversion to bf16 ----------------
__global__ __launch_bounds__(256) void k_convert(
    const float* __restrict__ kvw, const float* __restrict__ pw,
    const float* __restrict__ qp, ushort_t* __restrict__ wkv16,
    ushort_t* __restrict__ wp16, ushort_t* __restrict__ q16) {
  int i = blockIdx.x * 256 + threadIdx.x;
  if (i < 2 * C_ * C_) wkv16[i] = f2bf(kvw[i]);
  if (i < C_ * C_)     wp16[i]  = f2bf(pw[i]);
  if (i < M_ * H_ * DH_) {
    int d = i % DH_; int t = i / DH_; int h = t % H_; int m = t / H_;
    q16[((size_t)h * M_ + m) * DH_ + d] = f2bf(qp[i]);
  }
}

// ---------------- GEMM: 128x128 tile, BK=32, 4 waves (2x2). FOUR LDS buffers,
// depth-2 prefetch, ONE s_barrier per K-step (trailing barrier removed: with
// skew<=1 iter, fast wave writes buf[(t+3)&3] while slowest reads buf[t&3] --
// distinct mod 4; 3-buf could NOT drop it since 3 = 0 mod 3). vmcnt ladder
// 8/4/0. R8-verified both-sides XOR swizzle, R3-verified epilogue. ----------------
template <typename OutT, bool BIAS, bool SWZ>
__global__ __launch_bounds__(256) void k_gemm_bt(
    const ushort_t* __restrict__ A, const ushort_t* __restrict__ Bw,
    OutT* __restrict__ Co, const float* __restrict__ bias,
    int M, int N, int K, int ntn) {
  __shared__ ushort_t lA[4][128 * 32];
  __shared__ ushort_t lB[4][128 * 32];
  int bid = blockIdx.x;
  if (SWZ) bid = (bid & 7) * (gridDim.x >> 3) + (bid >> 3);
  int tr = bid / ntn, tc = bid % ntn;
  int tid = threadIdx.x;
  int w = tid >> 6, l = tid & 63;
  int wr = w >> 1, wc = w & 1;
  int c = l & 15, g = l >> 4;
  f32x4 acc[4][4];
#pragma unroll
  for (int i = 0; i < 4; ++i)
#pragma unroll
    for (int j = 0; j < 4; ++j) acc[i][j] = (f32x4){0.f, 0.f, 0.f, 0.f};
  const size_t a0 = (size_t)tr * 128, b0 = (size_t)tc * 128;
  int srow = l >> 2;
  int scol = (((l & 3) ^ ((l >> 3) & 3))) * 8;   // inverse-swizzled source block
  const int rsw = (c >> 1) & 3;                  // read-side swizzle key
  const int T = K >> 5;
#define STAGE32(buf, kt)                                                          \
  {                                                                               \
    _Pragma("unroll")                                                             \
    for (int r = 0; r < 2; ++r) {                                                 \
      int lr = w * 16 + r * 64;                                                   \
      gload_lds16(A  + (a0 + lr + srow) * (size_t)K + (kt) + scol,                \
                  &lA[buf][lr * 32]);                                             \
      gload_lds16(Bw + (b0 + lr + srow) * (size_t)K + (kt) + scol,                \
                  &lB[buf][lr * 32]);                                             \
    }                                                                             \
  }
  // prologue: tiles 0 and 1 in flight (8 loads/wave)
  STAGE32(0, 0)
  if (T > 1) STAGE32(1, 32)
  for (int t = 0; t < T; ++t) {
    int cur = t & 3;
    if (t + 2 < T) {
      STAGE32((t + 2) & 3, (t + 2) << 5)
      asm volatile("s_waitcnt vmcnt(8)" ::: "memory");   // drain tile t's 4 loads
    } else if (t + 1 < T) {
      asm volatile("s_waitcnt vmcnt(4)" ::: "memory");
    } else {
      asm volatile("s_waitcnt vmcnt(0)" ::: "memory");
    }
    __builtin_amdgcn_sched_barrier(0);
    __builtin_amdgcn_s_barrier();      // single barrier per K-step
    s16x8 af[4], bf[4];
#pragma unroll
    for (int i = 0; i < 4; ++i) {
      int row = wr * 64 + i * 16 + c;
      af[i] = *(const s16x8*)&lA[cur][row * 32 + ((unsigned)(g ^ rsw)) * 8];
    }
#pragma unroll
    for (int j = 0; j < 4; ++j) {
      int row = wc * 64 + j * 16 + c;
      bf[j] = *(const s16x8*)&lB[cur][row * 32 + ((unsigned)(g ^ rsw)) * 8];
    }
#pragma unroll
    for (int i = 0; i < 4; ++i)
#pragma unroll
      for (int j = 0; j < 4; ++j)
        acc[i][j] = mfma_16x16x32(af[i], bf[j], acc[i][j]);
  }
#undef STAGE32
  // R3-verified epilogue: lane holds C[rows g*4+q][col c] per 16x16 tile
#pragma unroll
  for (int i = 0; i < 4; ++i) {
#pragma unroll
    for (int j = 0; j < 4; ++j) {
      size_t col = b0 + wc * 64 + j * 16 + c;
      float bs = BIAS ? bias[col] : 0.0f;
#pragma unroll
      for (int q = 0; q < 4; ++q) {
        size_t row = a0 + wr * 64 + i * 16 + g * 4 + q;
        float v = acc[i][j][q] + bs;
        if constexpr (sizeof(OutT) == 2) Co[row * N + col] = f2bf(v);
        else                             Co[row * N + col] = v;
      }
    }
  }
}

// ---------------- flash attention: ONE 512-thread block per (b,h) ----------------
// (R13-verified, byte-identical) 8 waves; wave 7 = padding rows -> skips compute.
// T12 cvt_pk P-pack, T13 defer-max.
__global__ __launch_bounds__(512) void k_attn(
    const ushort_t* __restrict__ kv, const ushort_t* __restrict__ q16,
    ushort_t* __restrict__ att16) {
  int bh = blockIdx.x;
  int b = bh >> 3, h = bh & 7;
  __shared__ ushort_t Kl[2][64 * 72];   // [buf][n][dh(64 pad)] stride 72
  __shared__ ushort_t Vt[2][48 * 76];   // [buf][d][n] stride 76
  int tid = threadIdx.x;
  int w = tid >> 6, l = tid & 63;
  int c = l & 15, g = l >> 4;
  for (int i = tid; i < 2 * 64 * 72; i += 512) ((ushort_t*)Kl)[i] = 0;
  s16x8 qf[2][2];
#pragma unroll
  for (int i = 0; i < 2; ++i)
#pragma unroll
    for (int kk = 0; kk < 2; ++kk) {
      int m = w * 32 + i * 16 + c;
      int dh = kk * 32 + g * 8;
      s16x8 z = {0, 0, 0, 0, 0, 0, 0, 0};
      qf[i][kk] = (m < M_ && dh < DH_)
                      ? *(const s16x8*)(q16 + ((size_t)h * M_ + m) * DH_ + dh)
                      : z;
    }
  f32x4 o[3][2];
#pragma unroll
  for (int f = 0; f < 3; ++f)
#pragma unroll
    for (int i = 0; i < 2; ++i) o[f][i] = (f32x4){0.f, 0.f, 0.f, 0.f};
  float rm[2] = {-3e38f, -3e38f}, rl[2] = {0.f, 0.f};
  int srow = tid >> 3, spart = tid & 7;
  const size_t rowstride = (size_t)(2 * C_);
  const size_t gbase = (size_t)b * N_ * rowstride + h * DH_ + spart * 6;
  uint32_t kr0, kr1, kr2, vr0, vr1, vr2;
  {
    const ushort_t* p = kv + gbase + (size_t)srow * rowstride;
    kr0 = *(const uint32_t*)(p);
    kr1 = *(const uint32_t*)(p + 2);
    kr2 = *(const uint32_t*)(p + 4);
    vr0 = *(const uint32_t*)(p + C_);
    vr1 = *(const uint32_t*)(p + C_ + 2);
    vr2 = *(const uint32_t*)(p + C_ + 4);
  }
  __syncthreads();  // zero-init visible before first LDS write

  for (int t = 0; t < 49; ++t) {
    int p = t & 1;
    uint32_t* kd = (uint32_t*)&Kl[p][srow * 72 + spart * 6];
    kd[0] = kr0; kd[1] = kr1; kd[2] = kr2;
    int dbase = spart * 6;
    ushort_t* vt = &Vt[p][0];
    vt[(dbase + 0) * 76 + srow] = (ushort_t)vr0;
    vt[(dbase + 1) * 76 + srow] = (ushort_t)(vr0 >> 16);
    vt[(dbase + 2) * 76 + srow] = (ushort_t)vr1;
    vt[(dbase + 3) * 76 + srow] = (ushort_t)(vr1 >> 16);
    vt[(dbase + 4) * 76 + srow] = (ushort_t)vr2;
    vt[(dbase + 5) * 76 + srow] = (ushort_t)(vr2 >> 16);
    __syncthreads();   // single barrier per tile (dbuf)
    {
      int tn = (t < 48) ? t + 1 : t;
      const ushort_t* pp = kv + gbase + ((size_t)tn * 64 + srow) * rowstride;
      kr0 = *(const uint32_t*)(pp);
      kr1 = *(const uint32_t*)(pp + 2);
      kr2 = *(const uint32_t*)(pp + 4);
      vr0 = *(const uint32_t*)(pp + C_);
      vr1 = *(const uint32_t*)(pp + C_ + 2);
      vr2 = *(const uint32_t*)(pp + C_ + 4);
    }
    if (w < 7) {   // wave 7 = all padding rows: skip compute, keep staging+barriers
      f32x4 s[4][2];
      __builtin_amdgcn_s_setprio(1);
#pragma unroll
      for (int j = 0; j < 4; ++j) {
        s16x8 kf0 = *(const s16x8*)&Kl[p][(j * 16 + c) * 72 + g * 8];
        s16x8 kf1 = *(const s16x8*)&Kl[p][(j * 16 + c) * 72 + 32 + g * 8];
#pragma unroll
        for (int i = 0; i < 2; ++i) {
          f32x4 z = {0.f, 0.f, 0.f, 0.f};
          f32x4 t0 = mfma_16x16x32(kf0, qf[i][0], z);
          s[j][i] = mfma_16x16x32(kf1, qf[i][1], t0);
        }
      }
      __builtin_amdgcn_s_setprio(0);
      s16x4 pb[2][4];
#pragma unroll
      for (int i = 0; i < 2; ++i) {
        float tm = s[0][i][0];
#pragma unroll
        for (int j = 0; j < 4; ++j)
#pragma unroll
          for (int q = 0; q < 4; ++q) tm = fmaxf(tm, s[j][i][q]);
        tm = fmaxf(tm, __shfl_xor(tm, 16));
        tm = fmaxf(tm, __shfl_xor(tm, 32));
        if (__any(tm > rm[i] + 8.f)) {
          float nm = fmaxf(rm[i], tm);
          float corr = __expf(rm[i] - nm);
          rl[i] *= corr;
#pragma unroll
          for (int f = 0; f < 3; ++f) o[f][i] *= corr;
          rm[i] = nm;
        }
        float m_i = rm[i];
        float ts = 0.f;
#pragma unroll
        for (int j = 0; j < 4; ++j) {
          float p0 = __expf(s[j][i][0] - m_i);
          float p1 = __expf(s[j][i][1] - m_i);
          float p2 = __expf(s[j][i][2] - m_i);
          float p3 = __expf(s[j][i][3] - m_i);
          ts += (p0 + p1) + (p2 + p3);
          uint32_t* pp = (uint32_t*)&pb[i][j];
          pp[0] = pkbf(p0, p1);
          pp[1] = pkbf(p2, p3);
        }
        ts += __shfl_xor(ts, 16);
        ts += __shfl_xor(ts, 32);
        rl[i] += ts;
      }
      __builtin_amdgcn_s_setprio(1);
#pragma unroll
      for (int f = 0; f < 3; ++f)
#pragma unroll
        for (int j = 0; j < 4; ++j) {
          s16x4 vf = *(const s16x4*)&Vt[p][(f * 16 + c) * 76 + j * 16 + g * 4];
          o[f][0] = mfma_16x16x16(vf, pb[0][j], o[f][0]);
          o[f][1] = mfma_16x16x16(vf, pb[1][j], o[f][1]);
        }
      __builtin_amdgcn_s_setprio(0);
    }
  }
  // epilogue: lane holds O^T[d = f*16+g*4+q][m]
#pragma unroll
  for (int i = 0; i < 2; ++i) {
    int m = w * 32 + i * 16 + c;
    if (m < M_) {
      float inv = 1.0f / rl[i];
#pragma unroll
      for (int f = 0; f < 3; ++f) {
        uint32_t w0 = (uint32_t)f2bf_fast(o[f][i][0] * inv) |
                      ((uint32_t)f2bf_fast(o[f][i][1] * inv) << 16);
        uint32_t w1 = (uint32_t)f2bf_fast(o[f][i][2] * inv) |
                      ((uint32_t)f2bf_fast(o[f][i][3] * inv) << 16);
        uint2 val; val.x = w0; val.y = w1;
        *(uint2*)&att16[((size_t)b * M_ + m) * C_ + h * DH_ + f * 16 + g * 4] = val;
      }
    }
  }
}

extern "C" void kernel_launch(void* const* d_in, const int* in_sizes, int n_in,
                              void* d_out, int out_size, void* d_ws, size_t ws_size,
                              hipStream_t stream) {
  (void)in_sizes; (void)n_in; (void)out_size; (void)ws_size;
  const float* x   = (const float*)d_in[0];
  const float* qp  = (const float*)d_in[1];
  const float* kvw = (const float*)d_in[2];
  const float* pw  = (const float*)d_in[3];
  const float* pbv = (const float*)d_in[4];
  const float* lnw = (const float*)d_in[5];
  const float* lnb = (const float*)d_in[6];
  float* out = (float*)d_out;

  ushort_t* x16   = (ushort_t*)d_ws;
  ushort_t* kv16  = x16 + (size_t)ROWS * C_;
  ushort_t* att16 = kv16 + (size_t)ROWS * 2 * C_;
  ushort_t* wkv16 = att16 + (size_t)PROWS * C_;
  ushort_t* wp16  = wkv16 + 2 * C_ * C_;
  ushort_t* q16   = wp16 + C_ * C_;

  hipLaunchKernelGGL(k_ln_gelu, dim3(ROWS / 4), dim3(256), 0, stream, x, lnw, lnb, x16);
  hipLaunchKernelGGL(k_convert, dim3((2 * C_ * C_ + 255) / 256), dim3(256), 0, stream,
                     kvw, pw, qp, wkv16, wp16, q16);
  hipLaunchKernelGGL((k_gemm_bt<ushort_t, false, true>),
                     dim3((ROWS / 128) * (2 * C_ / 128)), dim3(256), 0, stream,
                     x16, wkv16, kv16, (const float*)nullptr, ROWS, 2 * C_, C_, 2 * C_ / 128);
  hipLaunchKernelGGL(k_attn, dim3(B_ * H_), dim3(512), 0, stream, kv16, q16, att16);
  hipLaunchKernelGGL((k_gemm_bt<float, true, false>),
                     dim3((PROWS / 128) * (C_ / 128)), dim3(256), 0, stream,
                     att16, wp16, out, pbv, PROWS, C_, C_, C_ / 128);
}

// Round 19
// 254.771 us; speedup vs baseline: 1.0089x; 1.0089x over previous
//
#include <hip/hip_runtime.h>
#include <stdint.h>

typedef float f32x4 __attribute__((ext_vector_type(4)));
typedef short s16x8 __attribute__((ext_vector_type(8)));
typedef short s16x4 __attribute__((ext_vector_type(4)));
typedef unsigned short ushort_t;

#define B_  32
#define N_  3136
#define C_  384
#define H_  8
#define DH_ 48
#define M_  196
#define ROWS  (B_*N_)   // 100352
#define PROWS (B_*M_)   // 6272
#define KVB   112       // 3136 = 28 * 112 exactly
#define NT    28
#define VSTR  124       // Vt stride: conflict-free (30c mod 32, cycle 16)

// RNE bf16 (reference-grade)
static __device__ __forceinline__ ushort_t f2bf(float f) {
  union { float f; uint32_t u; } v; v.f = f;
  uint32_t r = (v.u + 0x7fffu + ((v.u >> 16) & 1u)) >> 16;
  return (ushort_t)r;
}
// round-half-up bf16: 2 VALU inst; differs from RNE only on exact ties
static __device__ __forceinline__ ushort_t f2bf_fast(float f) {
  union { float f; uint32_t u; } v; v.f = f;
  return (ushort_t)((v.u + 0x8000u) >> 16);
}
// packed f32x2 -> bf16x2, T12-verified recipe (m214v22)
static __device__ __forceinline__ uint32_t pkbf(float lo, float hi) {
  uint32_t r;
  asm("v_cvt_pk_bf16_f32 %0, %1, %2" : "=v"(r) : "v"(lo), "v"(hi));
  return r;
}

static __device__ __forceinline__ f32x4 mfma_16x16x32(s16x8 a, s16x8 b, f32x4 c) {
  return __builtin_amdgcn_mfma_f32_16x16x32_bf16(a, b, c, 0, 0, 0);
}

static __device__ __forceinline__ f32x4 mfma_16x16x16(s16x4 a, s16x4 b, f32x4 c) {
#if __has_builtin(__builtin_amdgcn_mfma_f32_16x16x16_bf16)
  return __builtin_amdgcn_mfma_f32_16x16x16_bf16(a, b, c, 0, 0, 0);
#elif __has_builtin(__builtin_amdgcn_mfma_f32_16x16x16bf16_1k)
  return __builtin_amdgcn_mfma_f32_16x16x16bf16_1k(a, b, c, 0, 0, 0);
#else
  f32x4 d;
  asm("v_mfma_f32_16x16x16_bf16 %0, %1, %2, %3" : "=v"(d) : "v"(a), "v"(b), "v"(c));
  return d;
#endif
}

static __device__ __forceinline__ void gload_lds16(const void* g, void* l) {
  __builtin_amdgcn_global_load_lds(
      (const __attribute__((address_space(1))) void*)(uintptr_t)g,
      (__attribute__((address_space(3))) void*)(uint32_t)(uintptr_t)l,
      16, 0, 0);
}

// ---------------- LayerNorm + exact GELU, fp32 -> bf16 ----------------
__global__ __launch_bounds__(256) void k_ln_gelu(
    const float* __restrict__ x, const float* __restrict__ lnw,
    const float* __restrict__ lnb, ushort_t* __restrict__ x16) {
  int row = blockIdx.x * 4 + (threadIdx.x >> 6);
  int lane = threadIdx.x & 63;
  const float2* xr = (const float2*)(x + (size_t)row * C_);
  float2 v0 = xr[lane], v1 = xr[lane + 64], v2 = xr[lane + 128];
  float s  = v0.x + v0.y + v1.x + v1.y + v2.x + v2.y;
  float ss = v0.x*v0.x + v0.y*v0.y + v1.x*v1.x + v1.y*v1.y + v2.x*v2.x + v2.y*v2.y;
#pragma unroll
  for (int off = 1; off < 64; off <<= 1) {
    s  += __shfl_xor(s, off);
    ss += __shfl_xor(ss, off);
  }
  float mu = s * (1.0f / C_);
  float rs = rsqrtf(ss * (1.0f / C_) - mu * mu + 1e-6f);
  const float2* wr = (const float2*)lnw;
  const float2* br = (const float2*)lnb;
  uint32_t* outp = (uint32_t*)(x16 + (size_t)row * C_);
#pragma unroll
  for (int t = 0; t < 3; ++t) {
    int idx = lane + t * 64;
    float2 v = (t == 0) ? v0 : ((t == 1) ? v1 : v2);
    float2 w = wr[idx], bb = br[idx];
    float a0 = (v.x - mu) * rs * w.x + bb.x;
    float a1 = (v.y - mu) * rs * w.y + bb.y;
    a0 = 0.5f * a0 * (1.0f + erff(a0 * 0.70710678118654752440f));
    a1 = 0.5f * a1 * (1.0f + erff(a1 * 0.70710678118654752440f));
    outp[idx] = (uint32_t)f2bf_fast(a0) | ((uint32_t)f2bf_fast(a1) << 16);
  }
}

// ---------------- weight/query conversion to bf16 ----------------
__global__ __launch_bounds__(256) void k_convert(
    const float* __restrict__ kvw, const float* __restrict__ pw,
    const float* __restrict__ qp, ushort_t* __restrict__ wkv16,
    ushort_t* __restrict__ wp16, ushort_t* __restrict__ q16) {
  int i = blockIdx.x * 256 + threadIdx.x;
  if (i < 2 * C_ * C_) wkv16[i] = f2bf(kvw[i]);
  if (i < C_ * C_)     wp16[i]  = f2bf(pw[i]);
  if (i < M_ * H_ * DH_) {
    int d = i % DH_; int t = i / DH_; int h = t % H_; int m = t / H_;
    q16[((size_t)h * M_ + m) * DH_ + d] = f2bf(qp[i]);
  }
}

// ---------------- GEMM (R15-EXACT, bench-verified 101.5 us): 128x128 tile,
// BK=32, 512 threads = 8 waves (2x4), per-wave 64x32 (acc[4][2]=32 AGPR,
// 4 waves/SIMD, 71% occupancy). 2-buf counted vmcnt(2), both-sides XOR swizzle.
template <typename OutT, bool BIAS, bool SWZ>
__global__ __launch_bounds__(512, 4) void k_gemm_bt(
    const ushort_t* __restrict__ A, const ushort_t* __restrict__ Bw,
    OutT* __restrict__ Co, const float* __restrict__ bias,
    int M, int N, int K, int ntn) {
  __shared__ ushort_t lA[2][128 * 32];
  __shared__ ushort_t lB[2][128 * 32];
  int bid = blockIdx.x;
  if (SWZ) bid = (bid & 7) * (gridDim.x >> 3) + (bid >> 3);
  int tr = bid / ntn, tc = bid % ntn;
  int tid = threadIdx.x;
  int w = tid >> 6, l = tid & 63;
  int wr = w >> 2, wc = w & 3;           // 2 wave-rows x 4 wave-cols
  int c = l & 15, g = l >> 4;
  f32x4 acc[4][2];
#pragma unroll
  for (int i = 0; i < 4; ++i)
#pragma unroll
    for (int j = 0; j < 2; ++j) acc[i][j] = (f32x4){0.f, 0.f, 0.f, 0.f};
  const size_t a0 = (size_t)tr * 128, b0 = (size_t)tc * 128;
  int srow = w * 16 + (l >> 2);
  int ssrc = ((l & 3) ^ ((l >> 3) & 3)) * 8;
  const int rsw = (c >> 1) & 3;
  const int T = K >> 5;
#define STAGE32(buf, kt)                                                          \
  {                                                                               \
    gload_lds16(A  + (a0 + srow) * (size_t)K + (kt) + ssrc,                       \
                &lA[buf][w * 512]);                                               \
    gload_lds16(Bw + (b0 + srow) * (size_t)K + (kt) + ssrc,                       \
                &lB[buf][w * 512]);                                               \
  }
  STAGE32(0, 0)
  for (int t = 0; t < T; ++t) {
    int cur = t & 1;
    if (t + 1 < T) {
      STAGE32(cur ^ 1, (t + 1) << 5)
      asm volatile("s_waitcnt vmcnt(2)" ::: "memory");   // drain tile t's 2 loads
    } else {
      asm volatile("s_waitcnt vmcnt(0)" ::: "memory");
    }
    __builtin_amdgcn_sched_barrier(0);
    __builtin_amdgcn_s_barrier();      // buf[cur] visible
    s16x8 af[4], bf[2];
#pragma unroll
    for (int i = 0; i < 4; ++i) {
      int row = wr * 64 + i * 16 + c;
      af[i] = *(const s16x8*)&lA[cur][row * 32 + ((unsigned)(g ^ rsw)) * 8];
    }
#pragma unroll
    for (int j = 0; j < 2; ++j) {
      int row = wc * 32 + j * 16 + c;
      bf[j] = *(const s16x8*)&lB[cur][row * 32 + ((unsigned)(g ^ rsw)) * 8];
    }
#pragma unroll
    for (int i = 0; i < 4; ++i)
#pragma unroll
      for (int j = 0; j < 2; ++j)
        acc[i][j] = mfma_16x16x32(af[i], bf[j], acc[i][j]);
    __builtin_amdgcn_sched_barrier(0);
    __builtin_amdgcn_s_barrier();      // reads done before overwrite
  }
#undef STAGE32
  // R3-verified epilogue mapping: lane holds C[rows g*4+q][col c] per 16x16 tile
#pragma unroll
  for (int i = 0; i < 4; ++i) {
#pragma unroll
    for (int j = 0; j < 2; ++j) {
      size_t col = b0 + wc * 32 + j * 16 + c;
      float bs = BIAS ? bias[col] : 0.0f;
#pragma unroll
      for (int q = 0; q < 4; ++q) {
        size_t row = a0 + wr * 64 + i * 16 + g * 4 + q;
        float v = acc[i][j][q] + bs;
        if constexpr (sizeof(OutT) == 2) Co[row * N + col] = f2bf(v);
        else                             Co[row * N + col] = v;
      }
    }
  }
}

// ---------------- flash attention: ONE 512-thread block per (b,h) ----------------
// KVBLK=112 (3136 = 28*112 exact, no tail): barriers 49->28, prefetch bursts
// halved. 8 waves; wave 7 = padding rows -> skips compute. K/V double-buffered,
// one __syncthreads per tile; T12 cvt_pk P-pack; T13 defer-max.
__global__ __launch_bounds__(512) void k_attn(
    const ushort_t* __restrict__ kv, const ushort_t* __restrict__ q16,
    ushort_t* __restrict__ att16) {
  int bh = blockIdx.x;
  int b = bh >> 3, h = bh & 7;
  __shared__ ushort_t Kl[2][KVB * 72];    // [buf][n][dh(64 pad)] stride 72
  __shared__ ushort_t Vt[2][48 * VSTR];   // [buf][d][n] stride 124
  int tid = threadIdx.x;
  int w = tid >> 6, l = tid & 63;
  int c = l & 15, g = l >> 4;
  for (int i = tid; i < 2 * KVB * 72; i += 512) ((ushort_t*)Kl)[i] = 0;
  s16x8 qf[2][2];
#pragma unroll
  for (int i = 0; i < 2; ++i)
#pragma unroll
    for (int kk = 0; kk < 2; ++kk) {
      int m = w * 32 + i * 16 + c;
      int dh = kk * 32 + g * 8;
      s16x8 z = {0, 0, 0, 0, 0, 0, 0, 0};
      qf[i][kk] = (m < M_ && dh < DH_)
                      ? *(const s16x8*)(q16 + ((size_t)h * M_ + m) * DH_ + dh)
                      : z;
    }
  f32x4 o[3][2];
#pragma unroll
  for (int f = 0; f < 3; ++f)
#pragma unroll
    for (int i = 0; i < 2; ++i) o[f][i] = (f32x4){0.f, 0.f, 0.f, 0.f};
  float rm[2] = {-3e38f, -3e38f}, rl[2] = {0.f, 0.f};
  // staging: srow = tid>>2 (0..127, active < 112), spart = tid&3 (12 shorts each)
  int srow = tid >> 2, spart = tid & 3;
  const bool act = srow < KVB;
  const size_t rowstride = (size_t)(2 * C_);
  const size_t gbase = (size_t)b * N_ * rowstride + h * DH_ + spart * 12;
  uint2 kA, kB, kC, vA, vB, vC;
  if (act) {
    const ushort_t* p = kv + gbase + (size_t)srow * rowstride;
    kA = *(const uint2*)(p);      kB = *(const uint2*)(p + 4);  kC = *(const uint2*)(p + 8);
    vA = *(const uint2*)(p + C_); vB = *(const uint2*)(p + C_ + 4); vC = *(const uint2*)(p + C_ + 8);
  }
  __syncthreads();  // zero-init visible before first LDS write

  for (int t = 0; t < NT; ++t) {
    int p = t & 1;
    if (act) {
      uint2* kd = (uint2*)&Kl[p][srow * 72 + spart * 12];
      kd[0] = kA; kd[1] = kB; kd[2] = kC;
      int dbase = spart * 12;
      ushort_t* vt = &Vt[p][0];
      vt[(dbase + 0) * VSTR + srow]  = (ushort_t)vA.x;
      vt[(dbase + 1) * VSTR + srow]  = (ushort_t)(vA.x >> 16);
      vt[(dbase + 2) * VSTR + srow]  = (ushort_t)vA.y;
      vt[(dbase + 3) * VSTR + srow]  = (ushort_t)(vA.y >> 16);
      vt[(dbase + 4) * VSTR + srow]  = (ushort_t)vB.x;
      vt[(dbase + 5) * VSTR + srow]  = (ushort_t)(vB.x >> 16);
      vt[(dbase + 6) * VSTR + srow]  = (ushort_t)vB.y;
      vt[(dbase + 7) * VSTR + srow]  = (ushort_t)(vB.y >> 16);
      vt[(dbase + 8) * VSTR + srow]  = (ushort_t)vC.x;
      vt[(dbase + 9) * VSTR + srow]  = (ushort_t)(vC.x >> 16);
      vt[(dbase + 10) * VSTR + srow] = (ushort_t)vC.y;
      vt[(dbase + 11) * VSTR + srow] = (ushort_t)(vC.y >> 16);
    }
    __syncthreads();   // single barrier per tile (dbuf)
    if (act) {
      int tn = (t < NT - 1) ? t + 1 : t;
      const ushort_t* pp = kv + gbase + ((size_t)tn * KVB + srow) * rowstride;
      kA = *(const uint2*)(pp);      kB = *(const uint2*)(pp + 4);  kC = *(const uint2*)(pp + 8);
      vA = *(const uint2*)(pp + C_); vB = *(const uint2*)(pp + C_ + 4); vC = *(const uint2*)(pp + C_ + 8);
    }
    if (w < 7) {   // wave 7 = all padding rows: skip compute, keep staging+barriers
      f32x4 s[7][2];
      __builtin_amdgcn_s_setprio(1);
#pragma unroll
      for (int j = 0; j < 7; ++j) {
        s16x8 kf0 = *(const s16x8*)&Kl[p][(j * 16 + c) * 72 + g * 8];
        s16x8 kf1 = *(const s16x8*)&Kl[p][(j * 16 + c) * 72 + 32 + g * 8];
#pragma unroll
        for (int i = 0; i < 2; ++i) {
          f32x4 z = {0.f, 0.f, 0.f, 0.f};
          f32x4 t0 = mfma_16x16x32(kf0, qf[i][0], z);
          s[j][i] = mfma_16x16x32(kf1, qf[i][1], t0);
        }
      }
      __builtin_amdgcn_s_setprio(0);
      s16x4 pb[2][7];
#pragma unroll
      for (int i = 0; i < 2; ++i) {
        float tm = s[0][i][0];
#pragma unroll
        for (int j = 0; j < 7; ++j)
#pragma unroll
          for (int q = 0; q < 4; ++q) tm = fmaxf(tm, s[j][i][q]);
        tm = fmaxf(tm, __shfl_xor(tm, 16));
        tm = fmaxf(tm, __shfl_xor(tm, 32));
        if (__any(tm > rm[i] + 8.f)) {
          float nm = fmaxf(rm[i], tm);
          float corr = __expf(rm[i] - nm);
          rl[i] *= corr;
#pragma unroll
          for (int f = 0; f < 3; ++f) o[f][i] *= corr;
          rm[i] = nm;
        }
        float m_i = rm[i];
        float ts = 0.f;
#pragma unroll
        for (int j = 0; j < 7; ++j) {
          float p0 = __expf(s[j][i][0] - m_i);
          float p1 = __expf(s[j][i][1] - m_i);
          float p2 = __expf(s[j][i][2] - m_i);
          float p3 = __expf(s[j][i][3] - m_i);
          ts += (p0 + p1) + (p2 + p3);
          uint32_t* pp = (uint32_t*)&pb[i][j];
          pp[0] = pkbf(p0, p1);
          pp[1] = pkbf(p2, p3);
        }
        ts += __shfl_xor(ts, 16);
        ts += __shfl_xor(ts, 32);
        rl[i] += ts;
      }
      __builtin_amdgcn_s_setprio(1);
#pragma unroll
      for (int f = 0; f < 3; ++f)
#pragma unroll
        for (int j = 0; j < 7; ++j) {
          s16x4 vf = *(const s16x4*)&Vt[p][(f * 16 + c) * VSTR + j * 16 + g * 4];
          o[f][0] = mfma_16x16x16(vf, pb[0][j], o[f][0]);
          o[f][1] = mfma_16x16x16(vf, pb[1][j], o[f][1]);
        }
      __builtin_amdgcn_s_setprio(0);
    }
  }
  // epilogue: lane holds O^T[d = f*16+g*4+q][m]
#pragma unroll
  for (int i = 0; i < 2; ++i) {
    int m = w * 32 + i * 16 + c;
    if (m < M_) {
      float inv = 1.0f / rl[i];
#pragma unroll
      for (int f = 0; f < 3; ++f) {
        uint32_t w0 = (uint32_t)f2bf_fast(o[f][i][0] * inv) |
                      ((uint32_t)f2bf_fast(o[f][i][1] * inv) << 16);
        uint32_t w1 = (uint32_t)f2bf_fast(o[f][i][2] * inv) |
                      ((uint32_t)f2bf_fast(o[f][i][3] * inv) << 16);
        uint2 val; val.x = w0; val.y = w1;
        *(uint2*)&att16[((size_t)b * M_ + m) * C_ + h * DH_ + f * 16 + g * 4] = val;
      }
    }
  }
}

extern "C" void kernel_launch(void* const* d_in, const int* in_sizes, int n_in,
                              void* d_out, int out_size, void* d_ws, size_t ws_size,
                              hipStream_t stream) {
  (void)in_sizes; (void)n_in; (void)out_size; (void)ws_size;
  const float* x   = (const float*)d_in[0];
  const float* qp  = (const float*)d_in[1];
  const float* kvw = (const float*)d_in[2];
  const float* pw  = (const float*)d_in[3];
  const float* pbv = (const float*)d_in[4];
  const float* lnw = (const float*)d_in[5];
  const float* lnb = (const float*)d_in[6];
  float* out = (float*)d_out;

  ushort_t* x16   = (ushort_t*)d_ws;
  ushort_t* kv16  = x16 + (size_t)ROWS * C_;
  ushort_t* att16 = kv16 + (size_t)ROWS * 2 * C_;
  ushort_t* wkv16 = att16 + (size_t)PROWS * C_;
  ushort_t* wp16  = wkv16 + 2 * C_ * C_;
  ushort_t* q16   = wp16 + C_ * C_;

  hipLaunchKernelGGL(k_ln_gelu, dim3(ROWS / 4), dim3(256), 0, stream, x, lnw, lnb, x16);
  hipLaunchKernelGGL(k_convert, dim3((2 * C_ * C_ + 255) / 256), dim3(256), 0, stream,
                     kvw, pw, qp, wkv16, wp16, q16);
  hipLaunchKernelGGL((k_gemm_bt<ushort_t, false, true>),
                     dim3((ROWS / 128) * (2 * C_ / 128)), dim3(512), 0, stream,
                     x16, wkv16, kv16, (const float*)nullptr, ROWS, 2 * C_, C_, 2 * C_ / 128);
  hipLaunchKernelGGL(k_attn, dim3(B_ * H_), dim3(512), 0, stream, kv16, q16, att16);
  hipLaunchKernelGGL((k_gemm_bt<float, true, false>),
                     dim3((PROWS / 128) * (C_ / 128)), dim3(512), 0, stream,
                     att16, wp16, out, pbv, PROWS, C_, C_, C_ / 128);
}

// Round 20
// 247.041 us; speedup vs baseline: 1.0405x; 1.0313x over previous
//
#include <hip/hip_runtime.h>
#include <stdint.h>

typedef float f32x4 __attribute__((ext_vector_type(4)));
typedef short s16x8 __attribute__((ext_vector_type(8)));
typedef short s16x4 __attribute__((ext_vector_type(4)));
typedef unsigned short ushort_t;

#define B_  32
#define N_  3136
#define C_  384
#define H_  8
#define DH_ 48
#define M_  196
#define ROWS  (B_*N_)   // 100352
#define PROWS (B_*M_)   // 6272

// RNE bf16 (reference-grade)
static __device__ __forceinline__ ushort_t f2bf(float f) {
  union { float f; uint32_t u; } v; v.f = f;
  uint32_t r = (v.u + 0x7fffu + ((v.u >> 16) & 1u)) >> 16;
  return (ushort_t)r;
}
// round-half-up bf16: 2 VALU inst; differs from RNE only on exact ties
static __device__ __forceinline__ ushort_t f2bf_fast(float f) {
  union { float f; uint32_t u; } v; v.f = f;
  return (ushort_t)((v.u + 0x8000u) >> 16);
}
// packed f32x2 -> bf16x2, T12-verified recipe (m214v22)
static __device__ __forceinline__ uint32_t pkbf(float lo, float hi) {
  uint32_t r;
  asm("v_cvt_pk_bf16_f32 %0, %1, %2" : "=v"(r) : "v"(lo), "v"(hi));
  return r;
}

static __device__ __forceinline__ f32x4 mfma_16x16x32(s16x8 a, s16x8 b, f32x4 c) {
  return __builtin_amdgcn_mfma_f32_16x16x32_bf16(a, b, c, 0, 0, 0);
}

static __device__ __forceinline__ f32x4 mfma_16x16x16(s16x4 a, s16x4 b, f32x4 c) {
#if __has_builtin(__builtin_amdgcn_mfma_f32_16x16x16_bf16)
  return __builtin_amdgcn_mfma_f32_16x16x16_bf16(a, b, c, 0, 0, 0);
#elif __has_builtin(__builtin_amdgcn_mfma_f32_16x16x16bf16_1k)
  return __builtin_amdgcn_mfma_f32_16x16x16bf16_1k(a, b, c, 0, 0, 0);
#else
  f32x4 d;
  asm("v_mfma_f32_16x16x16_bf16 %0, %1, %2, %3" : "=v"(d) : "v"(a), "v"(b), "v"(c));
  return d;
#endif
}

static __device__ __forceinline__ void gload_lds16(const void* g, void* l) {
  __builtin_amdgcn_global_load_lds(
      (const __attribute__((address_space(1))) void*)(uintptr_t)g,
      (__attribute__((address_space(3))) void*)(uint32_t)(uintptr_t)l,
      16, 0, 0);
}

// ---------------- LayerNorm + exact GELU, fp32 -> bf16 ----------------
__global__ __launch_bounds__(256) void k_ln_gelu(
    const float* __restrict__ x, const float* __restrict__ lnw,
    const float* __restrict__ lnb, ushort_t* __restrict__ x16) {
  int row = blockIdx.x * 4 + (threadIdx.x >> 6);
  int lane = threadIdx.x & 63;
  const float2* xr = (const float2*)(x + (size_t)row * C_);
  float2 v0 = xr[lane], v1 = xr[lane + 64], v2 = xr[lane + 128];
  float s  = v0.x + v0.y + v1.x + v1.y + v2.x + v2.y;
  float ss = v0.x*v0.x + v0.y*v0.y + v1.x*v1.x + v1.y*v1.y + v2.x*v2.x + v2.y*v2.y;
#pragma unroll
  for (int off = 1; off < 64; off <<= 1) {
    s  += __shfl_xor(s, off);
    ss += __shfl_xor(ss, off);
  }
  float mu = s * (1.0f / C_);
  float rs = rsqrtf(ss * (1.0f / C_) - mu * mu + 1e-6f);
  const float2* wr = (const float2*)lnw;
  const float2* br = (const float2*)lnb;
  uint32_t* outp = (uint32_t*)(x16 + (size_t)row * C_);
#pragma unroll
  for (int t = 0; t < 3; ++t) {
    int idx = lane + t * 64;
    float2 v = (t == 0) ? v0 : ((t == 1) ? v1 : v2);
    float2 w = wr[idx], bb = br[idx];
    float a0 = (v.x - mu) * rs * w.x + bb.x;
    float a1 = (v.y - mu) * rs * w.y + bb.y;
    a0 = 0.5f * a0 * (1.0f + erff(a0 * 0.70710678118654752440f));
    a1 = 0.5f * a1 * (1.0f + erff(a1 * 0.70710678118654752440f));
    outp[idx] = (uint32_t)f2bf_fast(a0) | ((uint32_t)f2bf_fast(a1) << 16);
  }
}

// ---------------- weight/query conversion to bf16 ----------------
__global__ __launch_bounds__(256) void k_convert(
    const float* __restrict__ kvw, const float* __restrict__ pw,
    const float* __restrict__ qp, ushort_t* __restrict__ wkv16,
    ushort_t* __restrict__ wp16, ushort_t* __restrict__ q16) {
  int i = blockIdx.x * 256 + threadIdx.x;
  if (i < 2 * C_ * C_) wkv16[i] = f2bf(kvw[i]);
  if (i < C_ * C_)     wp16[i]  = f2bf(pw[i]);
  if (i < M_ * H_ * DH_) {
    int d = i % DH_; int t = i / DH_; int h = t % H_; int m = t / H_;
    q16[((size_t)h * M_ + m) * DH_ + d] = f2bf(qp[i]);
  }
}

// ---------------- GEMM (R15-EXACT, bench-verified): 128x128 tile, BK=32,
// 512 threads = 8 waves (2x4), per-wave 64x32 -> acc[4][2] = 32 AGPR;
// total regs ~64 -> 4 waves/SIMD (71% occupancy). 2-buf counted vmcnt(2),
// R8-verified both-sides XOR swizzle. ----------------
template <typename OutT, bool BIAS, bool SWZ>
__global__ __launch_bounds__(512, 4) void k_gemm_bt(
    const ushort_t* __restrict__ A, const ushort_t* __restrict__ Bw,
    OutT* __restrict__ Co, const float* __restrict__ bias,
    int M, int N, int K, int ntn) {
  __shared__ ushort_t lA[2][128 * 32];
  __shared__ ushort_t lB[2][128 * 32];
  int bid = blockIdx.x;
  if (SWZ) bid = (bid & 7) * (gridDim.x >> 3) + (bid >> 3);
  int tr = bid / ntn, tc = bid % ntn;
  int tid = threadIdx.x;
  int w = tid >> 6, l = tid & 63;
  int wr = w >> 2, wc = w & 3;           // 2 wave-rows x 4 wave-cols
  int c = l & 15, g = l >> 4;
  f32x4 acc[4][2];
#pragma unroll
  for (int i = 0; i < 4; ++i)
#pragma unroll
    for (int j = 0; j < 2; ++j) acc[i][j] = (f32x4){0.f, 0.f, 0.f, 0.f};
  const size_t a0 = (size_t)tr * 128, b0 = (size_t)tc * 128;
  int srow = w * 16 + (l >> 2);
  int ssrc = ((l & 3) ^ ((l >> 3) & 3)) * 8;
  const int rsw = (c >> 1) & 3;
  const int T = K >> 5;
#define STAGE32(buf, kt)                                                          \
  {                                                                               \
    gload_lds16(A  + (a0 + srow) * (size_t)K + (kt) + ssrc,                       \
                &lA[buf][w * 512]);                                               \
    gload_lds16(Bw + (b0 + srow) * (size_t)K + (kt) + ssrc,                       \
                &lB[buf][w * 512]);                                               \
  }
  STAGE32(0, 0)
  for (int t = 0; t < T; ++t) {
    int cur = t & 1;
    if (t + 1 < T) {
      STAGE32(cur ^ 1, (t + 1) << 5)
      asm volatile("s_waitcnt vmcnt(2)" ::: "memory");   // drain tile t's 2 loads
    } else {
      asm volatile("s_waitcnt vmcnt(0)" ::: "memory");
    }
    __builtin_amdgcn_sched_barrier(0);
    __builtin_amdgcn_s_barrier();      // buf[cur] visible
    s16x8 af[4], bf[2];
#pragma unroll
    for (int i = 0; i < 4; ++i) {
      int row = wr * 64 + i * 16 + c;
      af[i] = *(const s16x8*)&lA[cur][row * 32 + ((unsigned)(g ^ rsw)) * 8];
    }
#pragma unroll
    for (int j = 0; j < 2; ++j) {
      int row = wc * 32 + j * 16 + c;
      bf[j] = *(const s16x8*)&lB[cur][row * 32 + ((unsigned)(g ^ rsw)) * 8];
    }
#pragma unroll
    for (int i = 0; i < 4; ++i)
#pragma unroll
      for (int j = 0; j < 2; ++j)
        acc[i][j] = mfma_16x16x32(af[i], bf[j], acc[i][j]);
    __builtin_amdgcn_sched_barrier(0);
    __builtin_amdgcn_s_barrier();      // reads done before overwrite
  }
#undef STAGE32
  // R3-verified epilogue mapping: lane holds C[rows g*4+q][col c] per 16x16 tile
#pragma unroll
  for (int i = 0; i < 4; ++i) {
#pragma unroll
    for (int j = 0; j < 2; ++j) {
      size_t col = b0 + wc * 32 + j * 16 + c;
      float bs = BIAS ? bias[col] : 0.0f;
#pragma unroll
      for (int q = 0; q < 4; ++q) {
        size_t row = a0 + wr * 64 + i * 16 + g * 4 + q;
        float v = acc[i][j][q] + bs;
        if constexpr (sizeof(OutT) == 2) Co[row * N + col] = f2bf(v);
        else                             Co[row * N + col] = v;
      }
    }
  }
}

// ---------------- flash attention: ONE 512-thread block per (b,h) ----------------
// (R13-verified, byte-identical) 8 waves; wave 7 = padding rows -> skips compute.
// KVBLK=64, K/V double-buffered LDS, one __syncthreads per tile;
// T12 cvt_pk P-pack, T13 defer-max.
__global__ __launch_bounds__(512) void k_attn(
    const ushort_t* __restrict__ kv, const ushort_t* __restrict__ q16,
    ushort_t* __restrict__ att16) {
  int bh = blockIdx.x;
  int b = bh >> 3, h = bh & 7;
  __shared__ ushort_t Kl[2][64 * 72];   // [buf][n][dh(64 pad)] stride 72
  __shared__ ushort_t Vt[2][48 * 76];   // [buf][d][n] stride 76
  int tid = threadIdx.x;
  int w = tid >> 6, l = tid & 63;
  int c = l & 15, g = l >> 4;
  for (int i = tid; i < 2 * 64 * 72; i += 512) ((ushort_t*)Kl)[i] = 0;
  s16x8 qf[2][2];
#pragma unroll
  for (int i = 0; i < 2; ++i)
#pragma unroll
    for (int kk = 0; kk < 2; ++kk) {
      int m = w * 32 + i * 16 + c;
      int dh = kk * 32 + g * 8;
      s16x8 z = {0, 0, 0, 0, 0, 0, 0, 0};
      qf[i][kk] = (m < M_ && dh < DH_)
                      ? *(const s16x8*)(q16 + ((size_t)h * M_ + m) * DH_ + dh)
                      : z;
    }
  f32x4 o[3][2];
#pragma unroll
  for (int f = 0; f < 3; ++f)
#pragma unroll
    for (int i = 0; i < 2; ++i) o[f][i] = (f32x4){0.f, 0.f, 0.f, 0.f};
  float rm[2] = {-3e38f, -3e38f}, rl[2] = {0.f, 0.f};
  int srow = tid >> 3, spart = tid & 7;
  const size_t rowstride = (size_t)(2 * C_);
  const size_t gbase = (size_t)b * N_ * rowstride + h * DH_ + spart * 6;
  uint32_t kr0, kr1, kr2, vr0, vr1, vr2;
  {
    const ushort_t* p = kv + gbase + (size_t)srow * rowstride;
    kr0 = *(const uint32_t*)(p);
    kr1 = *(const uint32_t*)(p + 2);
    kr2 = *(const uint32_t*)(p + 4);
    vr0 = *(const uint32_t*)(p + C_);
    vr1 = *(const uint32_t*)(p + C_ + 2);
    vr2 = *(const uint32_t*)(p + C_ + 4);
  }
  __syncthreads();  // zero-init visible before first LDS write

  for (int t = 0; t < 49; ++t) {
    int p = t & 1;
    uint32_t* kd = (uint32_t*)&Kl[p][srow * 72 + spart * 6];
    kd[0] = kr0; kd[1] = kr1; kd[2] = kr2;
    int dbase = spart * 6;
    ushort_t* vt = &Vt[p][0];
    vt[(dbase + 0) * 76 + srow] = (ushort_t)vr0;
    vt[(dbase + 1) * 76 + srow] = (ushort_t)(vr0 >> 16);
    vt[(dbase + 2) * 76 + srow] = (ushort_t)vr1;
    vt[(dbase + 3) * 76 + srow] = (ushort_t)(vr1 >> 16);
    vt[(dbase + 4) * 76 + srow] = (ushort_t)vr2;
    vt[(dbase + 5) * 76 + srow] = (ushort_t)(vr2 >> 16);
    __syncthreads();   // single barrier per tile (dbuf)
    {
      int tn = (t < 48) ? t + 1 : t;
      const ushort_t* pp = kv + gbase + ((size_t)tn * 64 + srow) * rowstride;
      kr0 = *(const uint32_t*)(pp);
      kr1 = *(const uint32_t*)(pp + 2);
      kr2 = *(const uint32_t*)(pp + 4);
      vr0 = *(const uint32_t*)(pp + C_);
      vr1 = *(const uint32_t*)(pp + C_ + 2);
      vr2 = *(const uint32_t*)(pp + C_ + 4);
    }
    if (w < 7) {   // wave 7 = all padding rows: skip compute, keep staging+barriers
      f32x4 s[4][2];
      __builtin_amdgcn_s_setprio(1);
#pragma unroll
      for (int j = 0; j < 4; ++j) {
        s16x8 kf0 = *(const s16x8*)&Kl[p][(j * 16 + c) * 72 + g * 8];
        s16x8 kf1 = *(const s16x8*)&Kl[p][(j * 16 + c) * 72 + 32 + g * 8];
#pragma unroll
        for (int i = 0; i < 2; ++i) {
          f32x4 z = {0.f, 0.f, 0.f, 0.f};
          f32x4 t0 = mfma_16x16x32(kf0, qf[i][0], z);
          s[j][i] = mfma_16x16x32(kf1, qf[i][1], t0);
        }
      }
      __builtin_amdgcn_s_setprio(0);
      s16x4 pb[2][4];
#pragma unroll
      for (int i = 0; i < 2; ++i) {
        float tm = s[0][i][0];
#pragma unroll
        for (int j = 0; j < 4; ++j)
#pragma unroll
          for (int q = 0; q < 4; ++q) tm = fmaxf(tm, s[j][i][q]);
        tm = fmaxf(tm, __shfl_xor(tm, 16));
        tm = fmaxf(tm, __shfl_xor(tm, 32));
        if (__any(tm > rm[i] + 8.f)) {
          float nm = fmaxf(rm[i], tm);
          float corr = __expf(rm[i] - nm);
          rl[i] *= corr;
#pragma unroll
          for (int f = 0; f < 3; ++f) o[f][i] *= corr;
          rm[i] = nm;
        }
        float m_i = rm[i];
        float ts = 0.f;
#pragma unroll
        for (int j = 0; j < 4; ++j) {
          float p0 = __expf(s[j][i][0] - m_i);
          float p1 = __expf(s[j][i][1] - m_i);
          float p2 = __expf(s[j][i][2] - m_i);
          float p3 = __expf(s[j][i][3] - m_i);
          ts += (p0 + p1) + (p2 + p3);
          uint32_t* pp = (uint32_t*)&pb[i][j];
          pp[0] = pkbf(p0, p1);
          pp[1] = pkbf(p2, p3);
        }
        ts += __shfl_xor(ts, 16);
        ts += __shfl_xor(ts, 32);
        rl[i] += ts;
      }
      __builtin_amdgcn_s_setprio(1);
#pragma unroll
      for (int f = 0; f < 3; ++f)
#pragma unroll
        for (int j = 0; j < 4; ++j) {
          s16x4 vf = *(const s16x4*)&Vt[p][(f * 16 + c) * 76 + j * 16 + g * 4];
          o[f][0] = mfma_16x16x16(vf, pb[0][j], o[f][0]);
          o[f][1] = mfma_16x16x16(vf, pb[1][j], o[f][1]);
        }
      __builtin_amdgcn_s_setprio(0);
    }
  }
  // epilogue: lane holds O^T[d = f*16+g*4+q][m]
#pragma unroll
  for (int i = 0; i < 2; ++i) {
    int m = w * 32 + i * 16 + c;
    if (m < M_) {
      float inv = 1.0f / rl[i];
#pragma unroll
      for (int f = 0; f < 3; ++f) {
        uint32_t w0 = (uint32_t)f2bf_fast(o[f][i][0] * inv) |
                      ((uint32_t)f2bf_fast(o[f][i][1] * inv) << 16);
        uint32_t w1 = (uint32_t)f2bf_fast(o[f][i][2] * inv) |
                      ((uint32_t)f2bf_fast(o[f][i][3] * inv) << 16);
        uint2 val; val.x = w0; val.y = w1;
        *(uint2*)&att16[((size_t)b * M_ + m) * C_ + h * DH_ + f * 16 + g * 4] = val;
      }
    }
  }
}

extern "C" void kernel_launch(void* const* d_in, const int* in_sizes, int n_in,
                              void* d_out, int out_size, void* d_ws, size_t ws_size,
                              hipStream_t stream) {
  (void)in_sizes; (void)n_in; (void)out_size; (void)ws_size;
  const float* x   = (const float*)d_in[0];
  const float* qp  = (const float*)d_in[1];
  const float* kvw = (const float*)d_in[2];
  const float* pw  = (const float*)d_in[3];
  const float* pbv = (const float*)d_in[4];
  const float* lnw = (const float*)d_in[5];
  const float* lnb = (const float*)d_in[6];
  float* out = (float*)d_out;

  ushort_t* x16   = (ushort_t*)d_ws;
  ushort_t* kv16  = x16 + (size_t)ROWS * C_;
  ushort_t* att16 = kv16 + (size_t)ROWS * 2 * C_;
  ushort_t* wkv16 = att16 + (size_t)PROWS * C_;
  ushort_t* wp16  = wkv16 + 2 * C_ * C_;
  ushort_t* q16   = wp16 + C_ * C_;

  hipLaunchKernelGGL(k_ln_gelu, dim3(ROWS / 4), dim3(256), 0, stream, x, lnw, lnb, x16);
  hipLaunchKernelGGL(k_convert, dim3((2 * C_ * C_ + 255) / 256), dim3(256), 0, stream,
                     kvw, pw, qp, wkv16, wp16, q16);
  hipLaunchKernelGGL((k_gemm_bt<ushort_t, false, true>),
                     dim3((ROWS / 128) * (2 * C_ / 128)), dim3(512), 0, stream,
                     x16, wkv16, kv16, (const float*)nullptr, ROWS, 2 * C_, C_, 2 * C_ / 128);
  hipLaunchKernelGGL(k_attn, dim3(B_ * H_), dim3(512), 0, stream, kv16, q16, att16);
  hipLaunchKernelGGL((k_gemm_bt<float, true, false>),
                     dim3((PROWS / 128) * (C_ / 128)), dim3(512), 0, stream,
                     att16, wp16, out, pbv, PROWS, C_, C_, C_ / 128);
}